// Round 16
// baseline (542.805 us; speedup 1.0000x reference)
//
#include <hip/hip_runtime.h>

// VQ argmin: exact bit-level emulation of numpy fp32 reference:
//   A  = np.sum(flat*flat, axis=1)     (numpy pairwise-sum tree, fp32)
//   M2 = (2*flat) @ emb.T              (BLAS: sequential fp32 fma chain over d)
//   dist = (A - M2) + ee;  argmin_k (first-min ties)
// z_e_x: [B=16, D=256, H=64, W=64] fp32; embedding: [K=1024, D=256] fp32
// out: int32 [65536]
//
// R18: spend R17's freed registers on occupancy. R17 proved the hot loop
// is spill-free at ~52 VGPR but stayed grid-capped at 4 blocks/CU (Occ 37%,
// VALU 65%: 4 waves/SIMD can't hide er/z latency; R17's per-supertile
// butterfly also serialized into the 65%-busy pipe, +40us). Changes:
//  - KL=2 (acc 32 + er pp 8 + temps ~55 VGPR <= 64) -> launch_bounds(256,8)
//    = 8 waves/SIMD, the lever R4/R5 could never fit.
//  - NSPLIT=2: wave handles 4 of 8 supertiles (k in [s*512,(s+1)*512)),
//    grid 2048 = 8 blocks/CU -> 32 waves/CU full residency.
//  - combine via proven memset + u64 (distbits,k) atomicMin + unpack
//    (R8/R11); butterfly (4/wave) now overlaps a busy VALU instead of
//    serializing.
// er: 16 FMA/load unchanged; L2 traffic stays 4GB (~17TB/s at target, half
// the 34.5 ceiling). z doubles to 128MB HBM -- trivial. Issue floor 218us.
// Exact: per-(n,k) fmaf chain d ascending; q ascending + strict <;
// butterfly u64 min ties->lowest k; global atomicMin = first-min
// (semantics verified absmax=0 in R8/R11/R13-R17). Prep unchanged.

#define D_DIM  256
#define K_DIM  1024
#define HW     4096
#define N_TOT  65536
#define NW     16                 // n's per wave
#define KL     2                  // k's per lane
#define NSPLIT 2                  // waves per n-group (k halves)
#define F32MAX 3.402823466e38f

// ---- fused prep: [0,256) et transpose | [256,768) A | [768,772) ee

__global__ void prep_kernel(const float* __restrict__ z, const float* __restrict__ e,
                            float* __restrict__ eT, float* __restrict__ A,
                            float* __restrict__ ee) {
#pragma clang fp contract(off)
    const int bid = blockIdx.x;
    const int t   = threadIdx.x;

    if (bid < 256) {
        // ---- transpose + fold the exact x2: eT[d][k] = 2*emb[k][d]
        __shared__ float tl[32][33];
        const int k0 = (bid & 31) * 32;
        const int d0 = (bid >> 5) * 32;
        const int tx = t & 31;
        const int ty = t >> 5;          // 0..7
        #pragma unroll
        for (int i = 0; i < 32; i += 8)
            tl[ty + i][tx] = 2.0f * e[(size_t)(k0 + ty + i) * D_DIM + d0 + tx];
        __syncthreads();
        #pragma unroll
        for (int i = 0; i < 32; i += 8)
            eT[(size_t)(d0 + ty + i) * K_DIM + k0 + tx] = tl[tx][ty + i];
    } else if (bid < 768) {
        // ---- A = numpy pairwise ||z_n||^2: 2 threads/n, one 128-half each
        // (independent 8-acc chains; total = s0 + s1). Bitwise-exact.
        const int tt = (bid - 256) * 256 + t;    // 0 .. 2*N_TOT-1
        const int n  = tt >> 1;
        const int h  = tt & 1;
        const int b  = n >> 12;
        const int hw = n & (HW - 1);
        const float* base = z + (size_t)b * D_DIM * HW + hw + (size_t)(h * 128) * HW;
        float r[8];
        #pragma unroll
        for (int j = 0; j < 8; ++j) { float v = base[(size_t)j * HW]; r[j] = v * v; }
        #pragma unroll
        for (int i = 8; i < 128; i += 8) {
            #pragma unroll
            for (int j = 0; j < 8; ++j) {
                float v = base[(size_t)(i + j) * HW];
                r[j] = r[j] + v * v;
            }
        }
        float s = ((r[0] + r[1]) + (r[2] + r[3])) + ((r[4] + r[5]) + (r[6] + r[7]));
        float other = __shfl_xor(s, 1);
        if (h == 0) A[n] = s + other;
    } else {
        // ---- ee = numpy pairwise ||e_k||^2 (two 128-halves of 8 accs)
        const int k = (bid - 768) * 256 + t;
        const float* row = e + (size_t)k * D_DIM;
        float total = 0.0f;
        #pragma unroll
        for (int h = 0; h < 2; ++h) {
            const float* a = row + h * 128;
            float r[8];
            #pragma unroll
            for (int j = 0; j < 8; ++j) { float v = a[j]; r[j] = v * v; }
            #pragma unroll
            for (int i = 8; i < 128; i += 8) {
                #pragma unroll
                for (int j = 0; j < 8; ++j) { float v = a[i + j]; r[j] = r[j] + v * v; }
            }
            float s = ((r[0] + r[1]) + (r[2] + r[3])) + ((r[4] + r[5]) + (r[6] + r[7]));
            total = (h == 0) ? s : (total + s);
        }
        ee[k] = total;
    }
}

// ---- main: wave owns 16 consecutive n (one b; z row = 64B contiguous,
// wave-uniform address -> compiler s_load_dwordx16) x 512 k (4 supertiles
// of 128; 2 per lane, stride 64). er: 2-row VGPR ping-pong (2 loads/row).
// Per 4-row iter: 8 er loads + 4 z s_loads + 128 v_fmac (256 cy).

__launch_bounds__(256, 8)
__global__ void vq_kernel(const float* __restrict__ z, const float* __restrict__ eT,
                          const float* __restrict__ A, const float* __restrict__ ee,
                          unsigned long long* __restrict__ packed) {
#pragma clang fp contract(off)
    const int lane = threadIdx.x & 63;
    const int wid  = __builtin_amdgcn_readfirstlane(threadIdx.x >> 6);
    const int s    = blockIdx.x & (NSPLIT - 1);  // k-half
    const int slab = blockIdx.x >> 1;            // 0..1023
    const int gw   = slab * 4 + wid;             // n-group 0..4095
    const int n0   = gw * NW;
    const int b    = n0 >> 12;                   // NW | 4096: never spans b
    const int hw0  = n0 & (HW - 1);
    const float* __restrict__ zrow = z + (size_t)b * D_DIM * HW + hw0;

    #pragma unroll 1
    for (int sst = 0; sst < 4; ++sst) {          // 4 supertiles of 128 k
        const int kb = (s * 4 + sst) * 64 * KL;
        const float* __restrict__ ep = eT + kb + lane;   // per-lane k base

        float acc[NW][KL];
        #pragma unroll
        for (int i = 0; i < NW; ++i)
            #pragma unroll
            for (int q = 0; q < KL; ++q) acc[i][q] = 0.0f;

        // er ping-pong buffers only (8 VGPR); z is consumed directly
        // (R14/R16-proven scalarization; NO arrays -> no spill).
        float ea[2][KL], eb[2][KL];
        #pragma unroll
        for (int r = 0; r < 2; ++r)
            #pragma unroll
            for (int q = 0; q < KL; ++q)
                ea[r][q] = ep[(size_t)r * K_DIM + q * 64];

        #pragma unroll 1
        for (int d = 0; d < D_DIM; d += 4) {
            // phase A: prefetch er rows d+2,d+3; compute rows d,d+1
            #pragma unroll
            for (int r = 0; r < 2; ++r)
                #pragma unroll
                for (int q = 0; q < KL; ++q)
                    eb[r][q] = ep[(size_t)(d + 2 + r) * K_DIM + q * 64];
            #pragma unroll
            for (int r = 0; r < 2; ++r) {
                const float* __restrict__ zr = zrow + (size_t)(d + r) * HW;
                #pragma unroll
                for (int i = 0; i < NW; ++i) {
                    const float zv = zr[i];          // uniform -> s_load
                    #pragma unroll
                    for (int q = 0; q < KL; ++q)
                        acc[i][q] = fmaf(zv, ea[r][q], acc[i][q]);
                }
            }
            // phase B: prefetch er rows d+4,d+5 (mask-wrap: tail values
            // dead, re-primed next supertile); compute rows d+2,d+3
            #pragma unroll
            for (int r = 0; r < 2; ++r) {
                const int dn = (d + 4 + r) & (D_DIM - 1);
                #pragma unroll
                for (int q = 0; q < KL; ++q)
                    ea[r][q] = ep[(size_t)dn * K_DIM + q * 64];
            }
            #pragma unroll
            for (int r = 0; r < 2; ++r) {
                const float* __restrict__ zr = zrow + (size_t)(d + 2 + r) * HW;
                #pragma unroll
                for (int i = 0; i < NW; ++i) {
                    const float zv = zr[i];          // uniform -> s_load
                    #pragma unroll
                    for (int q = 0; q < KL; ++q)
                        acc[i][q] = fmaf(zv, eb[r][q], acc[i][q]);
                }
            }
        }

        // fold supertile -> per-lane key -> 64-lane u64 butterfly min
        // (ties -> lowest k) -> lane0 global atomicMin. Butterfly overlaps
        // other waves' FMA (VALU busy at 8 waves/SIMD).
        #pragma unroll
        for (int i = 0; i < NW; ++i) {
            const float An = A[n0 + i];              // uniform, L1-hot
            unsigned int bkey = 0xFFFFFFFFu, bkk = 0u;
            #pragma unroll
            for (int q = 0; q < KL; ++q) {           // q ascending = k ascending
                const int kq = kb + q * 64 + lane;
                const float dist = (An - acc[i][q]) + ee[kq];
                unsigned int d32 = __float_as_uint(dist);
                d32 ^= (unsigned int)((int)d32 >> 31) | 0x80000000u;  // total order
                if (d32 < bkey) { bkey = d32; bkk = (unsigned int)kq; }
            }
            unsigned long long key =
                ((unsigned long long)bkey << 32) | (unsigned long long)bkk;
            #pragma unroll
            for (int m = 1; m < 64; m <<= 1) {
                unsigned long long o = __shfl_xor(key, m, 64);
                if (o < key) key = o;
            }
            if (lane == 0) atomicMin(&packed[n0 + i], key);
        }
    }
}

__global__ void unpack_kernel(const unsigned long long* __restrict__ packed,
                              int* __restrict__ out) {
    int n = blockIdx.x * blockDim.x + threadIdx.x;
    out[n] = (int)(packed[n] & 0xFFFFFFFFull);
}

extern "C" void kernel_launch(void* const* d_in, const int* in_sizes, int n_in,
                              void* d_out, int out_size, void* d_ws, size_t ws_size,
                              hipStream_t stream) {
    const float* z   = (const float*)d_in[0];   // [16,256,64,64]
    const float* emb = (const float*)d_in[1];   // [1024,256]
    int* out = (int*)d_out;                     // [65536] int32

    float* wsEE = (float*)d_ws;                 // 1024
    float* wsA  = wsEE + K_DIM;                 // 65536
    float* wsET = wsA + N_TOT;                  // 262144
    unsigned long long* wsPacked =
        (unsigned long long*)(wsET + (size_t)D_DIM * K_DIM);  // 65536 u64

    hipMemsetAsync(wsPacked, 0xFF, (size_t)N_TOT * sizeof(unsigned long long),
                   stream);
    prep_kernel<<<772, 256, 0, stream>>>(z, emb, wsET, wsA, wsEE);
    vq_kernel<<<(N_TOT / NW / 4) * NSPLIT, 256, 0, stream>>>(z, wsET, wsA, wsEE,
                                                             wsPacked);
    unpack_kernel<<<N_TOT / 256, 256, 0, stream>>>(wsPacked, out);
}